// Round 6
// baseline (317.896 us; speedup 1.0000x reference)
//
#include <hip/hip_runtime.h>
#include <hip/hip_bf16.h>
#include <stdint.h>

typedef __bf16 bf16x8 __attribute__((ext_vector_type(8)));
typedef float  f32x4  __attribute__((ext_vector_type(4)));
typedef unsigned short u16;
typedef u16 u16x8 __attribute__((ext_vector_type(8)));

__device__ __forceinline__ u16 f2b(float f) {
  uint32_t u = __builtin_bit_cast(uint32_t, f);
  u += 0x7fffu + ((u >> 16) & 1u);
  return (u16)(u >> 16);
}

__device__ __forceinline__ f32x4 mfma16(bf16x8 a, bf16x8 b, f32x4 c) {
  return __builtin_amdgcn_mfma_f32_16x16x32_bf16(a, b, c, 0, 0, 0);
}

__device__ __forceinline__ void gload_lds16(const void* g, void* l) {
  __builtin_amdgcn_global_load_lds(
      (const __attribute__((address_space(1))) void*)g,
      (__attribute__((address_space(3))) void*)l, 16, 0, 0);
}

#define BARRIER() asm volatile("s_barrier" ::: "memory")
#define LGKM0()   asm volatile("s_waitcnt lgkmcnt(0)" ::: "memory")

// ------------- merged fp32 -> bf16 convert (all 7 tensors, 1 launch) --------
__global__ void f2b_all(const float* __restrict__ x,  const float* __restrict__ wq,
                        const float* __restrict__ wk, const float* __restrict__ wv,
                        const float* __restrict__ wo, const float* __restrict__ w1,
                        const float* __restrict__ w2,
                        u16* __restrict__ xb, u16* __restrict__ wqkvb,
                        u16* __restrict__ wob, u16* __restrict__ w1b,
                        u16* __restrict__ w2b) {
  const int i = blockIdx.x * blockDim.x + threadIdx.x;  // elem8 index, 2097152 total
  const float* src; u16* dst; int off;
  if (i < 524288)        { src = x;  dst = xb;              off = i; }
  else if (i < 655360)   { src = wq; dst = wqkvb;           off = i - 524288; }
  else if (i < 786432)   { src = wk; dst = wqkvb + 1048576; off = i - 655360; }
  else if (i < 917504)   { src = wv; dst = wqkvb + 2097152; off = i - 786432; }
  else if (i < 1048576)  { src = wo; dst = wob;             off = i - 917504; }
  else if (i < 1572864)  { src = w1; dst = w1b;             off = i - 1048576; }
  else                   { src = w2; dst = w2b;             off = i - 1572864; }
  const float4* p = (const float4*)src + (size_t)off * 2;
  float4 a = p[0], b = p[1];
  u16x8 r;
  r[0] = f2b(a.x); r[1] = f2b(a.y); r[2] = f2b(a.z); r[3] = f2b(a.w);
  r[4] = f2b(b.x); r[5] = f2b(b.y); r[6] = f2b(b.z); r[7] = f2b(b.w);
  *((u16x8*)dst + off) = r;
}

// ---- 256x256 GEMM, BK=64, 4 phases/tile, counted vmcnt (T2+T3+T4+T5) ------
// LDS per operand: [2 dbuf][2 kk-half][256 rows][32 cols]; 16B slots 2-bit
// XOR-swizzled within each half. Staging unit = one kk-half of one operand
// (2 global_load_lds per thread), issued one per phase; the two per-tile
// waits vmcnt(4) always target loads issued >=2 phases earlier.
// MODE 0: QKV scatter (o0=q*(0.125*log2e), o1=k, o2=vt)   [no split]
// MODE 1: fp32 partial out, no bias (summed in ln_fused)  [split-k, sid->o0..o3]
// MODE 2: bf16 out + bias + exact gelu                    [no split]
template<int MODE>
__global__ __launch_bounds__(512, 2) void gemm256(
    const u16* __restrict__ A, const u16* __restrict__ W,
    const float* __restrict__ bias,
    void* __restrict__ o0, void* __restrict__ o1,
    void* __restrict__ o2, void* __restrict__ o3,
    int Nsz, int Kstride, int Klen, int ntiles)
{
  __shared__ u16 As[2][2][256 * 32];
  __shared__ u16 Bs[2][2][256 * 32];

  const int nbn = Nsz >> 8;
  int bid = blockIdx.x;
  bid = (bid & 7) * ((int)gridDim.x >> 3) + (bid >> 3);  // XCD swizzle (grid%8==0)
  const int tile = (MODE == 1) ? (bid % ntiles) : bid;
  const int sid  = (MODE == 1) ? (bid / ntiles) : 0;
  const int koff = sid * Klen;
  const int bm = tile / nbn;
  const int bn = tile % nbn;
  const int tid = threadIdx.x;
  const int w = tid >> 6, l = tid & 63;
  const int lh = l >> 4, ll = l & 15;
  const int wm = w >> 2, wn = w & 3;  // 2 x 4 waves; wave C-tile = 128x64

  f32x4 acc[8][4] = {};

  const u16* Ag = A + (size_t)(bm * 256) * Kstride + koff;
  const u16* Wg = W + (size_t)(bn * 256) * Kstride + koff;

  const int r0 = tid >> 2;              // staging row 0..127 (and +128)
  const int sg = (tid & 3) ^ (r0 & 3);  // pre-swizzled global slot (rule #21)
  const int NT = Klen >> 6;

  // stage half H of K-tile t: H = 0:A-kk0, 1:B-kk0, 2:A-kk1, 3:B-kk1
  auto stage = [&](int t, int H) {
    const int b = t & 1, kk = H >> 1;
    const u16* G = (H & 1) ? Wg : Ag;
    u16* D = (H & 1) ? &Bs[b][kk][0] : &As[b][kk][0];
    const size_t ce = (size_t)t * 64 + kk * 32 + sg * 8;
    gload_lds16(G + (size_t)r0 * Kstride + ce,         D + tid * 8);
    gload_lds16(G + (size_t)(r0 + 128) * Kstride + ce, D + (512 + tid) * 8);
  };

  // swizzled fragment reads (uniform 8 lanes per 4-bank group: conflict-free)
  auto dsA = [&](int p, int mi, int kk) -> bf16x8 {
    const int r = wm * 128 + mi * 16 + ll;
    return *(const bf16x8*)(&As[p][kk][0] + r * 32 + ((lh ^ (ll & 3)) * 8));
  };
  auto dsB = [&](int p, int ni, int kk) -> bf16x8 {
    const int r = wn * 64 + ni * 16 + ll;
    return *(const bf16x8*)(&Bs[p][kk][0] + r * 32 + ((lh ^ (ll & 3)) * 8));
  };

  // prologue: tile 0 fully staged and drained
  stage(0, 0); stage(0, 1); stage(0, 2); stage(0, 3);
  asm volatile("s_waitcnt vmcnt(0)" ::: "memory");
  BARRIER();

  bf16x8 aq[4], bq[4];
  for (int t = 0; t < NT; ++t) {
    const int p = t & 1;
    const bool st = (t + 1 < NT);

    // ---- phase 0: (mh=0, kk=0) ----
#pragma unroll
    for (int ni = 0; ni < 4; ++ni) bq[ni] = dsB(p, ni, 0);
#pragma unroll
    for (int m2 = 0; m2 < 4; ++m2) aq[m2] = dsA(p, m2, 0);
    if (st) stage(t + 1, 0);
    BARRIER(); LGKM0(); __builtin_amdgcn_sched_barrier(0);
    __builtin_amdgcn_s_setprio(1);
#pragma unroll
    for (int m2 = 0; m2 < 4; ++m2)
#pragma unroll
      for (int ni = 0; ni < 4; ++ni)
        acc[m2][ni] = mfma16(aq[m2], bq[ni], acc[m2][ni]);
    __builtin_amdgcn_s_setprio(0);
    BARRIER();

    // ---- phase 1: (mh=1, kk=0), reuse bq ----
#pragma unroll
    for (int m2 = 0; m2 < 4; ++m2) aq[m2] = dsA(p, 4 + m2, 0);
    if (st) stage(t + 1, 1);
    BARRIER(); LGKM0(); __builtin_amdgcn_sched_barrier(0);
    __builtin_amdgcn_s_setprio(1);
#pragma unroll
    for (int m2 = 0; m2 < 4; ++m2)
#pragma unroll
      for (int ni = 0; ni < 4; ++ni)
        acc[4 + m2][ni] = mfma16(aq[m2], bq[ni], acc[4 + m2][ni]);
    __builtin_amdgcn_s_setprio(0);
    // gate: tile t's kk=1 halves (staged 2-3 phases ago) must be landed
    if (st) asm volatile("s_waitcnt vmcnt(4)" ::: "memory");
    else    asm volatile("s_waitcnt vmcnt(0)" ::: "memory");
    BARRIER();

    // ---- phase 2: (mh=0, kk=1) ----
#pragma unroll
    for (int ni = 0; ni < 4; ++ni) bq[ni] = dsB(p, ni, 1);
#pragma unroll
    for (int m2 = 0; m2 < 4; ++m2) aq[m2] = dsA(p, m2, 1);
    if (st) stage(t + 1, 2);
    BARRIER(); LGKM0(); __builtin_amdgcn_sched_barrier(0);
    __builtin_amdgcn_s_setprio(1);
#pragma unroll
    for (int m2 = 0; m2 < 4; ++m2)
#pragma unroll
      for (int ni = 0; ni < 4; ++ni)
        acc[m2][ni] = mfma16(aq[m2], bq[ni], acc[m2][ni]);
    __builtin_amdgcn_s_setprio(0);
    BARRIER();

    // ---- phase 3: (mh=1, kk=1) ----
#pragma unroll
    for (int m2 = 0; m2 < 4; ++m2) aq[m2] = dsA(p, 4 + m2, 1);
    if (st) stage(t + 1, 3);
    BARRIER(); LGKM0(); __builtin_amdgcn_sched_barrier(0);
    __builtin_amdgcn_s_setprio(1);
#pragma unroll
    for (int m2 = 0; m2 < 4; ++m2)
#pragma unroll
      for (int ni = 0; ni < 4; ++ni)
        acc[4 + m2][ni] = mfma16(aq[m2], bq[ni], acc[4 + m2][ni]);
    __builtin_amdgcn_s_setprio(0);
    // gate: tile t+1's kk=0 halves (staged at phases 0-1) must be landed
    if (st) asm volatile("s_waitcnt vmcnt(4)" ::: "memory");
    else    asm volatile("s_waitcnt vmcnt(0)" ::: "memory");
    BARRIER();
  }

  // ---------------- epilogue ----------------
#pragma unroll
  for (int mi = 0; mi < 8; ++mi) {
#pragma unroll
    for (int ni = 0; ni < 4; ++ni) {
      const int col = bn * 256 + wn * 64 + ni * 16 + ll;
#pragma unroll
      for (int i = 0; i < 4; ++i) {
        const int row = bm * 256 + wm * 128 + mi * 16 + lh * 4 + i;
        float v = acc[mi][ni][i];
        if (MODE == 1) {
          float* dst = (sid == 0) ? (float*)o0 : (sid == 1) ? (float*)o1
                     : (sid == 2) ? (float*)o2 : (float*)o3;
          dst[(size_t)row * Nsz + col] = v;
        } else if (MODE == 2) {
          float xx = v + bias[col];
          float gl = 0.5f * xx * (1.0f + erff(xx * 0.70710678118654752f));
          ((u16*)o0)[(size_t)row * Nsz + col] = f2b(gl);
        } else {
          const int which = col >> 10;
          const int e = col & 1023;
          const int hh = e >> 6, dd = e & 63;
          const int bb = row >> 11, nl = row & 2047;
          if (which == 0) {  // q, pre-scaled by (1/sqrt(D)) * log2(e)
            ((u16*)o0)[((size_t)(bb * 16 + hh) * 2048 + nl) * 64 + dd] = f2b(v * 0.18033688f);
          } else if (which == 1) {
            ((u16*)o1)[((size_t)(bb * 16 + hh) * 2048 + nl) * 64 + dd] = f2b(v);
          } else {
            ((u16*)o2)[((size_t)(bb * 16 + hh) * 64 + dd) * 2048 + nl] = f2b(v);
          }
        }
      }
    }
  }
}

// ---------------- flash attention (non-causal), swapped QK^T, log2 domain ---
// Q,K: bf16 [32][2048][64] (Q pre-scaled); Vt: bf16 [32][64][2048]; ctx: bf16 [4096][1024]
__global__ __launch_bounds__(256, 4) void attn_fwd(
    const u16* __restrict__ Q, const u16* __restrict__ K,
    const u16* __restrict__ Vt, u16* __restrict__ ctx)
{
  __shared__ u16 Ks[2][64 * 64];
  __shared__ u16 Vs[2][64 * 64];
  __shared__ u16 Ps[4][16 * 64];

  const int bh = blockIdx.x & 31;
  const int qt = blockIdx.x >> 5;
  const int tid = threadIdx.x;
  const int w = tid >> 6, l = tid & 63;
  const int lh = l >> 4, ll = l & 15;
  const int q0 = qt * 64 + w * 16;

  bf16x8 qf[2];
  {
    const u16* Qg = Q + ((size_t)bh * 2048 + q0 + ll) * 64;
#pragma unroll
    for (int kk = 0; kk < 2; ++kk)
      qf[kk] = *(const bf16x8*)(Qg + kk * 32 + lh * 8);
  }

  bf16x8 ones;
  {
    const u16 o = 0x3F80;  // bf16 1.0
#pragma unroll
    for (int i = 0; i < 8; ++i) ones[i] = __builtin_bit_cast(__bf16, o);
  }

  f32x4 cacc[4] = {};
  f32x4 lacc = {};     // per-query row-sum of P (C-layout), via mfma(P, ones)
  float m_l = -1e30f;  // running max (log2 domain) for query ll
  u16* ps = Ps[w];

  const int f0 = tid, f1 = 256 + tid;
  const int r0 = f0 >> 3, s0 = f0 & 7, g0 = (s0 ^ (r0 & 7)) * 8;
  const int r1 = f1 >> 3, s1 = f1 & 7, g1 = (s1 ^ (r1 & 7)) * 8;

  // prologue: stage kt=0 into buf 0 (swizzled source, linear LDS dest)
  {
    gload_lds16(K + ((size_t)bh * 2048 + r0) * 64 + g0, Ks[0] + f0 * 8);
    gload_lds16(Vt + ((size_t)bh * 64 + r0) * 2048 + g0, Vs[0] + f0 * 8);
    gload_lds16(K + ((size_t)bh * 2048 + r1) * 64 + g1, Ks[0] + f1 * 8);
    gload_lds16(Vt + ((size_t)bh * 64 + r1) * 2048 + g1, Vs[0] + f1 * 8);
  }
  __syncthreads();

  for (int kt = 0; kt < 32; ++kt) {
    const int b = kt & 1;
    if (kt < 31) {  // stage kt+1 early; drains only at end-of-tile barrier
      const int kn = (kt + 1) * 64;
      gload_lds16(K + ((size_t)bh * 2048 + kn + r0) * 64 + g0, Ks[b ^ 1] + f0 * 8);
      gload_lds16(Vt + ((size_t)bh * 64 + r0) * 2048 + kn + g0, Vs[b ^ 1] + f0 * 8);
      gload_lds16(K + ((size_t)bh * 2048 + kn + r1) * 64 + g1, Ks[b ^ 1] + f1 * 8);
      gload_lds16(Vt + ((size_t)bh * 64 + r1) * 2048 + kn + g1, Vs[b ^ 1] + f1 * 8);
    }

    // S^T = K Q^T (log2 domain): lane holds S[key=jb*16+lh*4+i][q=ll]
    f32x4 st[4];
    __builtin_amdgcn_s_setprio(1);
#pragma unroll
    for (int jb = 0; jb < 4; ++jb) {
      f32x4 a = {};
#pragma unroll
      for (int kk = 0; kk < 2; ++kk) {
        const int r = jb * 16 + ll;
        bf16x8 kf = *(const bf16x8*)(Ks[b] + r * 64 + (((kk * 4 + lh) ^ (r & 7)) * 8));
        a = mfma16(kf, qf[kk], a);  // swapped: A=K, B=Q
      }
      st[jb] = a;
    }
    __builtin_amdgcn_s_setprio(0);

    // per-lane max over 16 regs + cross-lh reduce
    float mx = fmaxf(fmaxf(fmaxf(st[0][0], st[0][1]), fmaxf(st[0][2], st[0][3])),
                     fmaxf(fmaxf(st[1][0], st[1][1]), fmaxf(st[1][2], st[1][3])));
    mx = fmaxf(mx, fmaxf(fmaxf(fmaxf(st[2][0], st[2][1]), fmaxf(st[2][2], st[2][3])),
                         fmaxf(fmaxf(st[3][0], st[3][1]), fmaxf(st[3][2], st[3][3]))));
    mx = fmaxf(mx, __shfl_xor(mx, 16));
    mx = fmaxf(mx, __shfl_xor(mx, 32));

    // defer-max (T13): rescale only when max grew past threshold (log2 units)
    if (!__all(mx - m_l <= 8.0f)) {
      const float mn = fmaxf(m_l, mx);
      const float al = __builtin_amdgcn_exp2f(m_l - mn);
      m_l = mn;
      float alq[4];
#pragma unroll
      for (int i = 0; i < 4; ++i) alq[i] = __shfl(al, lh * 4 + i);
#pragma unroll
      for (int db = 0; db < 4; ++db)
#pragma unroll
        for (int i = 0; i < 4; ++i) cacc[db][i] *= alq[i];
#pragma unroll
      for (int i = 0; i < 4; ++i) lacc[i] *= alq[i];
    }

    // P = exp2(S - m), pack via v_cvt_pk_bf16_f32, store to wave-private LDS
#pragma unroll
    for (int jb = 0; jb < 4; ++jb) {
      const float p0 = __builtin_amdgcn_exp2f(st[jb][0] - m_l);
      const float p1 = __builtin_amdgcn_exp2f(st[jb][1] - m_l);
      const float p2 = __builtin_amdgcn_exp2f(st[jb][2] - m_l);
      const float p3 = __builtin_amdgcn_exp2f(st[jb][3] - m_l);
      uint2 pk;
      asm("v_cvt_pk_bf16_f32 %0, %1, %2" : "=v"(pk.x) : "v"(p0), "v"(p1));
      asm("v_cvt_pk_bf16_f32 %0, %1, %2" : "=v"(pk.y) : "v"(p2), "v"(p3));
      *(uint2*)(ps + ll * 64 + (((jb * 2 + (lh >> 1)) ^ (ll & 7)) * 8) + (lh & 1) * 4) = pk;
    }

    asm volatile("s_waitcnt lgkmcnt(0)" ::: "memory");
    __builtin_amdgcn_sched_barrier(0);

    // ctx += P * V ; row-sums l += P @ 1 (same A-fragment, free B)
    __builtin_amdgcn_s_setprio(1);
#pragma unroll
    for (int kk = 0; kk < 2; ++kk) {
      bf16x8 pf = *(const bf16x8*)(ps + ll * 64 + (((kk * 4 + lh) ^ (ll & 7)) * 8));
      lacc = mfma16(pf, ones, lacc);
#pragma unroll
      for (int db = 0; db < 4; ++db) {
        const int vr = db * 16 + ll;
        bf16x8 vf = *(const bf16x8*)(Vs[b] + vr * 64 + (((kk * 4 + lh) ^ (vr & 7)) * 8));
        cacc[db] = mfma16(pf, vf, cacc[db]);
      }
    }
    __builtin_amdgcn_s_setprio(0);
    __syncthreads();  // drains staged loads for kt+1, protects dbuf
  }

  const int bb = bh >> 4, hh = bh & 15;
#pragma unroll
  for (int db = 0; db < 4; ++db)
#pragma unroll
    for (int i = 0; i < 4; ++i) {
      const float v = cacc[db][i] / lacc[i];
      const size_t orow = (size_t)bb * 2048 + q0 + lh * 4 + i;
      const size_t ocol = (size_t)hh * 64 + db * 16 + ll;
      ctx[orow * 1024 + ocol] = f2b(v);
    }
}

// --- fused residual + up-to-4 partials + bias + LayerNorm (row = 1024 f32) --
__global__ __launch_bounds__(256) void ln_fused(
    const float* __restrict__ a,  const float* __restrict__ b0,
    const float* __restrict__ b1, const float* __restrict__ b2,
    const float* __restrict__ b3, const float* __restrict__ bias,
    const float* __restrict__ g,  const float* __restrict__ be,
    float* __restrict__ ho, u16* __restrict__ hb)
{
  const int row = blockIdx.x;
  const int t = threadIdx.x;
  const size_t base = (size_t)row * 1024 + t * 4;
  float4 xa = *(const float4*)(a + base);
  float4 xb = *(const float4*)(b0 + base);
  float v0 = xa.x + xb.x, v1 = xa.y + xb.y, v2 = xa.z + xb.z, v3 = xa.w + xb.w;
  if (b1) {
    float4 xc = *(const float4*)(b1 + base);
    v0 += xc.x; v1 += xc.y; v2 += xc.z; v3 += xc.w;
  }
  if (b2) {
    float4 xc = *(const float4*)(b2 + base);
    v0 += xc.x; v1 += xc.y; v2 += xc.z; v3 += xc.w;
  }
  if (b3) {
    float4 xc = *(const float4*)(b3 + base);
    v0 += xc.x; v1 += xc.y; v2 += xc.z; v3 += xc.w;
  }
  if (bias) {
    float4 xd = *(const float4*)(bias + t * 4);
    v0 += xd.x; v1 += xd.y; v2 += xd.z; v3 += xd.w;
  }
  float s = v0 + v1 + v2 + v3;
  float ss = v0 * v0 + v1 * v1 + v2 * v2 + v3 * v3;
#pragma unroll
  for (int d = 1; d < 64; d <<= 1) {
    s += __shfl_xor(s, d);
    ss += __shfl_xor(ss, d);
  }
  __shared__ float red[8];
  const int w = t >> 6, lid = t & 63;
  if (lid == 0) { red[w] = s; red[4 + w] = ss; }
  __syncthreads();
  s = red[0] + red[1] + red[2] + red[3];
  ss = red[4] + red[5] + red[6] + red[7];
  const float mean = s * (1.0f / 1024.0f);
  const float var = ss * (1.0f / 1024.0f) - mean * mean;
  const float rstd = rsqrtf(var + 1e-5f);
  const float vv[4] = {v0, v1, v2, v3};
#pragma unroll
  for (int i = 0; i < 4; ++i) {
    const int col = t * 4 + i;
    const float hv = (vv[i] - mean) * rstd * g[col] + be[col];
    if (ho) ho[base + i] = hv;
    if (hb) hb[base + i] = f2b(hv);
  }
}

// ---------------------------------------------------------------------------
extern "C" void kernel_launch(void* const* d_in, const int* in_sizes, int n_in,
                              void* d_out, int out_size, void* d_ws, size_t ws_size,
                              hipStream_t stream) {
  const float* x   = (const float*)d_in[0];
  const float* wq  = (const float*)d_in[1];
  const float* wk  = (const float*)d_in[2];
  const float* wv  = (const float*)d_in[3];
  const float* wo  = (const float*)d_in[4];
  const float* bo  = (const float*)d_in[5];
  const float* g1  = (const float*)d_in[6];
  const float* b1  = (const float*)d_in[7];
  const float* w1  = (const float*)d_in[8];
  const float* bf1 = (const float*)d_in[9];
  const float* w2  = (const float*)d_in[10];
  const float* bf2 = (const float*)d_in[11];
  const float* g2  = (const float*)d_in[12];
  const float* b2  = (const float*)d_in[13];

  char* ws = (char*)d_ws;
  const size_t MB = 1u << 20;
  // liveness plan (producer -> last consumer); NO overlapping live ranges:
  u16* xb    = (u16*)(ws + 0);           //  0-8   conv -> QKV
  u16* wqkv  = (u16*)(ws + 8 * MB);      //  8-14  conv -> QKV
  u16* wob   = (u16*)(ws + 14 * MB);     // 14-16  conv -> WO
  u16* w1b   = (u16*)(ws + 16 * MB);     // 16-24  conv -> FF1
  u16* w2b   = (u16*)(ws + 24 * MB);     // 24-32  conv -> FF2
  u16* qb    = (u16*)(ws + 32 * MB);     // 32-40  QKV -> attn
  u16* kb    = (u16*)(ws + 40 * MB);     // 40-48  QKV -> attn
  u16* vtb   = (u16*)(ws + 48 * MB);     // 48-56  QKV -> attn
  u16* ctxb  = (u16*)(ws + 56 * MB);     // 56-64  attn -> WO
  float* pA   = (float*)(ws + 64 * MB);  // 64-80  WO p0 -> LN1; FF2 p0 -> LN2
  float* hbuf = (float*)(ws + 80 * MB);  // 80-96  LN1 -> LN2
  u16* hbb   = (u16*)(ws + 96 * MB);     // 96-104 LN1 -> FF1
  float* wo_p1 = (float*)(ws + 32 * MB); // 32-48  WO p1 -> LN1 (qb/kb dead)
  u16* ff1   = (u16*)(ws + 32 * MB);     // 32-64  FF1 -> FF2 (wo_p1/vtb/ctxb dead)
  float* f2_p1 = (float*)(ws + 0);       //  0-16  FF2 p1 -> LN2 (xb/wqkv/wob dead)

  // all fp32 -> bf16 conversions in one launch
  f2b_all<<<8192, 256, 0, stream>>>(x, wq, wk, wv, wo, w1, w2, xb, wqkv, wob, w1b, w2b);

  // fused QKV projection (q pre-scaled by 0.125*log2e): M=4096 N=3072 K=1024
  gemm256<0><<<192, 512, 0, stream>>>(xb, wqkv, nullptr, qb, kb, vtb, nullptr,
                                      3072, 1024, 1024, 0);
  // attention
  attn_fwd<<<1024, 256, 0, stream>>>(qb, kb, vtb, ctxb);
  // output projection, split-k=2 (bias bo folded into LN1): M=4096 N=1024 K=1024
  gemm256<1><<<128, 512, 0, stream>>>(ctxb, wob, nullptr, pA, wo_p1, nullptr, nullptr,
                                      1024, 1024, 512, 64);
  // h = LN(x + wo_p0 + wo_p1 + bo)
  ln_fused<<<4096, 256, 0, stream>>>(x, pA, wo_p1, nullptr, nullptr, bo, g1, b1, hbuf, hbb);
  // ff1 = gelu(h @ w1^T + bf1): M=4096 N=4096 K=1024
  gemm256<2><<<256, 512, 0, stream>>>(hbb, w1b, bf1, ff1, nullptr, nullptr, nullptr,
                                      4096, 1024, 1024, 0);
  // ff2 = ff1 @ w2^T, split-k=2 (bias bf2 folded into LN2): M=4096 N=1024 K=4096
  gemm256<1><<<128, 512, 0, stream>>>(ff1, w2b, nullptr, pA, f2_p1, nullptr, nullptr,
                                      1024, 4096, 2048, 64);
  // out = LN(h + p0 + p1 + bf2)
  ln_fused<<<4096, 256, 0, stream>>>(hbuf, pA, f2_p1, nullptr, nullptr, bf2, g2, b2,
                                     (float*)d_out, nullptr);
}

// Round 7
// 267.886 us; speedup vs baseline: 1.1867x; 1.1867x over previous
//
#include <hip/hip_runtime.h>
#include <hip/hip_bf16.h>
#include <stdint.h>

typedef __bf16 bf16x8 __attribute__((ext_vector_type(8)));
typedef float  f32x4  __attribute__((ext_vector_type(4)));
typedef unsigned short u16;
typedef u16 u16x8 __attribute__((ext_vector_type(8)));

__device__ __forceinline__ u16 f2b(float f) {
  uint32_t u = __builtin_bit_cast(uint32_t, f);
  u += 0x7fffu + ((u >> 16) & 1u);
  return (u16)(u >> 16);
}

__device__ __forceinline__ f32x4 mfma16(bf16x8 a, bf16x8 b, f32x4 c) {
  return __builtin_amdgcn_mfma_f32_16x16x32_bf16(a, b, c, 0, 0, 0);
}

__device__ __forceinline__ void gload_lds16(const void* g, void* l) {
  __builtin_amdgcn_global_load_lds(
      (const __attribute__((address_space(1))) void*)g,
      (__attribute__((address_space(3))) void*)l, 16, 0, 0);
}

// ------------- merged fp32 -> bf16 convert (all 7 tensors, 1 launch) --------
__global__ void f2b_all(const float* __restrict__ x,  const float* __restrict__ wq,
                        const float* __restrict__ wk, const float* __restrict__ wv,
                        const float* __restrict__ wo, const float* __restrict__ w1,
                        const float* __restrict__ w2,
                        u16* __restrict__ xb, u16* __restrict__ wqkvb,
                        u16* __restrict__ wob, u16* __restrict__ w1b,
                        u16* __restrict__ w2b) {
  const int i = blockIdx.x * blockDim.x + threadIdx.x;  // elem8 index, 2097152 total
  const float* src; u16* dst; int off;
  if (i < 524288)        { src = x;  dst = xb;              off = i; }
  else if (i < 655360)   { src = wq; dst = wqkvb;           off = i - 524288; }
  else if (i < 786432)   { src = wk; dst = wqkvb + 1048576; off = i - 655360; }
  else if (i < 917504)   { src = wv; dst = wqkvb + 2097152; off = i - 786432; }
  else if (i < 1048576)  { src = wo; dst = wob;             off = i - 917504; }
  else if (i < 1572864)  { src = w1; dst = w1b;             off = i - 1048576; }
  else                   { src = w2; dst = w2b;             off = i - 1572864; }
  const float4* p = (const float4*)src + (size_t)off * 2;
  float4 a = p[0], b = p[1];
  u16x8 r;
  r[0] = f2b(a.x); r[1] = f2b(a.y); r[2] = f2b(a.z); r[3] = f2b(a.w);
  r[4] = f2b(b.x); r[5] = f2b(b.y); r[6] = f2b(b.z); r[7] = f2b(b.w);
  *((u16x8*)dst + off) = r;
}

// ---------------- GEMM (PROVEN round-3 structure): 128x128, BK=32, 2-phase --
// C[M][N] = A[M][K] * W[N][K]^T
// MODE 0: QKV scatter (o0=q*(0.125*log2e), o1=k, o2=vt)  [no split]
// MODE 1: fp32 partial out, NO bias (summed in ln_fused)  [split-k via ntiles]
// MODE 2: bf16 out + bias + exact gelu                    [no split]
template<int MODE>
__global__ __launch_bounds__(256, 3) void gemm_bt(
    const u16* __restrict__ A, const u16* __restrict__ W,
    const float* __restrict__ bias,
    void* __restrict__ o0, void* __restrict__ o1, void* __restrict__ o2,
    int Nsz, int Kstride, int Klen, int ntiles)
{
  __shared__ u16 As[2][128 * 32];
  __shared__ u16 Bs[2][128 * 32];
  const int nbn = Nsz >> 7;
  int bid = blockIdx.x;
  bid = (bid & 7) * ((int)gridDim.x >> 3) + (bid >> 3);  // XCD-aware swizzle (grid%8==0)
  const int tile = (MODE == 1) ? (bid % ntiles) : bid;
  const int sid  = (MODE == 1) ? (bid / ntiles) : 0;
  const int koff = sid * Klen;
  const int bm = tile / nbn;
  const int bn = tile % nbn;
  const int tid = threadIdx.x;
  const int w = tid >> 6, l = tid & 63;
  const int lh = l >> 4, ll = l & 15;
  const int wr = w >> 1, wc = w & 1;

  f32x4 acc[4][4] = {};

  const u16* Ag = A + (size_t)(bm * 128) * Kstride + koff;
  const u16* Wg = W + (size_t)(bn * 128) * Kstride + koff;

  const int flat0 = (w * 2) * 64 + l;
  const int flat1 = (w * 2 + 1) * 64 + l;

  // prologue: stage k-step 0 into buf 0
  {
    gload_lds16(Ag + (size_t)(flat0 >> 2) * Kstride + (flat0 & 3) * 8, As[0] + flat0 * 8);
    gload_lds16(Wg + (size_t)(flat0 >> 2) * Kstride + (flat0 & 3) * 8, Bs[0] + flat0 * 8);
    gload_lds16(Ag + (size_t)(flat1 >> 2) * Kstride + (flat1 & 3) * 8, As[0] + flat1 * 8);
    gload_lds16(Wg + (size_t)(flat1 >> 2) * Kstride + (flat1 & 3) * 8, Bs[0] + flat1 * 8);
  }
  __syncthreads();

  const int NS = Klen >> 5;
  int buf = 0;
  for (int s = 0; s < NS; ++s) {
    if (s + 1 < NS) {  // issue next-tile stage first (loads fly under compute)
      const int k0 = (s + 1) * 32;
      gload_lds16(Ag + (size_t)(flat0 >> 2) * Kstride + k0 + (flat0 & 3) * 8, As[buf ^ 1] + flat0 * 8);
      gload_lds16(Wg + (size_t)(flat0 >> 2) * Kstride + k0 + (flat0 & 3) * 8, Bs[buf ^ 1] + flat0 * 8);
      gload_lds16(Ag + (size_t)(flat1 >> 2) * Kstride + k0 + (flat1 & 3) * 8, As[buf ^ 1] + flat1 * 8);
      gload_lds16(Wg + (size_t)(flat1 >> 2) * Kstride + k0 + (flat1 & 3) * 8, Bs[buf ^ 1] + flat1 * 8);
    }
    bf16x8 af[4], bfr[4];
#pragma unroll
    for (int mi = 0; mi < 4; ++mi)
      af[mi] = *(const bf16x8*)(As[buf] + (wr * 64 + mi * 16 + ll) * 32 + lh * 8);
#pragma unroll
    for (int ni = 0; ni < 4; ++ni)
      bfr[ni] = *(const bf16x8*)(Bs[buf] + (wc * 64 + ni * 16 + ll) * 32 + lh * 8);
    __builtin_amdgcn_s_setprio(1);
#pragma unroll
    for (int mi = 0; mi < 4; ++mi)
#pragma unroll
      for (int ni = 0; ni < 4; ++ni)
        acc[mi][ni] = mfma16(af[mi], bfr[ni], acc[mi][ni]);
    __builtin_amdgcn_s_setprio(0);
    __syncthreads();  // drains vmcnt for staged buf^1 + protects dbuf reuse
    buf ^= 1;
  }

#pragma unroll
  for (int mi = 0; mi < 4; ++mi) {
#pragma unroll
    for (int ni = 0; ni < 4; ++ni) {
      const int col = bn * 128 + wc * 64 + ni * 16 + ll;
#pragma unroll
      for (int i = 0; i < 4; ++i) {
        const int row = bm * 128 + wr * 64 + mi * 16 + lh * 4 + i;
        float v = acc[mi][ni][i];
        if (MODE == 1) {
          float* dst = sid ? (float*)o1 : (float*)o0;
          dst[(size_t)row * Nsz + col] = v;
        } else if (MODE == 2) {
          float xx = v + bias[col];
          float gl = 0.5f * xx * (1.0f + erff(xx * 0.70710678118654752f));
          ((u16*)o0)[(size_t)row * Nsz + col] = f2b(gl);
        } else {
          const int which = col >> 10;
          const int e = col & 1023;
          const int hh = e >> 6, dd = e & 63;
          const int bb = row >> 11, nl = row & 2047;
          if (which == 0) {  // q, pre-scaled by (1/sqrt(D)) * log2(e)
            ((u16*)o0)[((size_t)(bb * 16 + hh) * 2048 + nl) * 64 + dd] = f2b(v * 0.18033688f);
          } else if (which == 1) {
            ((u16*)o1)[((size_t)(bb * 16 + hh) * 2048 + nl) * 64 + dd] = f2b(v);
          } else {
            ((u16*)o2)[((size_t)(bb * 16 + hh) * 64 + dd) * 2048 + nl] = f2b(v);
          }
        }
      }
    }
  }
}

// ---------------- flash attention (non-causal), swapped QK^T, log2 domain ---
// Q,K: bf16 [32][2048][64] (Q pre-scaled); Vt: bf16 [32][64][2048]; ctx: bf16 [4096][1024]
__global__ __launch_bounds__(256, 4) void attn_fwd(
    const u16* __restrict__ Q, const u16* __restrict__ K,
    const u16* __restrict__ Vt, u16* __restrict__ ctx)
{
  __shared__ u16 Ks[2][64 * 64];
  __shared__ u16 Vs[2][64 * 64];
  __shared__ u16 Ps[4][16 * 64];

  const int bh = blockIdx.x & 31;
  const int qt = blockIdx.x >> 5;
  const int tid = threadIdx.x;
  const int w = tid >> 6, l = tid & 63;
  const int lh = l >> 4, ll = l & 15;
  const int q0 = qt * 64 + w * 16;

  bf16x8 qf[2];
  {
    const u16* Qg = Q + ((size_t)bh * 2048 + q0 + ll) * 64;
#pragma unroll
    for (int kk = 0; kk < 2; ++kk)
      qf[kk] = *(const bf16x8*)(Qg + kk * 32 + lh * 8);
  }

  bf16x8 ones;
  {
    const u16 o = 0x3F80;  // bf16 1.0
#pragma unroll
    for (int i = 0; i < 8; ++i) ones[i] = __builtin_bit_cast(__bf16, o);
  }

  f32x4 cacc[4] = {};
  f32x4 lacc = {};     // per-query row-sum of P (C-layout), via mfma(P, ones)
  float m_l = -1e30f;  // running max (log2 domain) for query ll
  u16* ps = Ps[w];

  const int f0 = tid, f1 = 256 + tid;
  const int r0 = f0 >> 3, s0 = f0 & 7, g0 = (s0 ^ (r0 & 7)) * 8;
  const int r1 = f1 >> 3, s1 = f1 & 7, g1 = (s1 ^ (r1 & 7)) * 8;

  // prologue: stage kt=0 into buf 0 (swizzled source, linear LDS dest)
  {
    gload_lds16(K + ((size_t)bh * 2048 + r0) * 64 + g0, Ks[0] + f0 * 8);
    gload_lds16(Vt + ((size_t)bh * 64 + r0) * 2048 + g0, Vs[0] + f0 * 8);
    gload_lds16(K + ((size_t)bh * 2048 + r1) * 64 + g1, Ks[0] + f1 * 8);
    gload_lds16(Vt + ((size_t)bh * 64 + r1) * 2048 + g1, Vs[0] + f1 * 8);
  }
  __syncthreads();

  for (int kt = 0; kt < 32; ++kt) {
    const int b = kt & 1;
    if (kt < 31) {  // stage kt+1 early; drains only at end-of-tile barrier
      const int kn = (kt + 1) * 64;
      gload_lds16(K + ((size_t)bh * 2048 + kn + r0) * 64 + g0, Ks[b ^ 1] + f0 * 8);
      gload_lds16(Vt + ((size_t)bh * 64 + r0) * 2048 + kn + g0, Vs[b ^ 1] + f0 * 8);
      gload_lds16(K + ((size_t)bh * 2048 + kn + r1) * 64 + g1, Ks[b ^ 1] + f1 * 8);
      gload_lds16(Vt + ((size_t)bh * 64 + r1) * 2048 + kn + g1, Vs[b ^ 1] + f1 * 8);
    }

    // S^T = K Q^T (log2 domain): lane holds S[key=jb*16+lh*4+i][q=ll]
    f32x4 st[4];
    __builtin_amdgcn_s_setprio(1);
#pragma unroll
    for (int jb = 0; jb < 4; ++jb) {
      f32x4 a = {};
#pragma unroll
      for (int kk = 0; kk < 2; ++kk) {
        const int r = jb * 16 + ll;
        bf16x8 kf = *(const bf16x8*)(Ks[b] + r * 64 + (((kk * 4 + lh) ^ (r & 7)) * 8));
        a = mfma16(kf, qf[kk], a);  // swapped: A=K, B=Q
      }
      st[jb] = a;
    }
    __builtin_amdgcn_s_setprio(0);

    // per-lane max over 16 regs + cross-lh reduce
    float mx = fmaxf(fmaxf(fmaxf(st[0][0], st[0][1]), fmaxf(st[0][2], st[0][3])),
                     fmaxf(fmaxf(st[1][0], st[1][1]), fmaxf(st[1][2], st[1][3])));
    mx = fmaxf(mx, fmaxf(fmaxf(fmaxf(st[2][0], st[2][1]), fmaxf(st[2][2], st[2][3])),
                         fmaxf(fmaxf(st[3][0], st[3][1]), fmaxf(st[3][2], st[3][3]))));
    mx = fmaxf(mx, __shfl_xor(mx, 16));
    mx = fmaxf(mx, __shfl_xor(mx, 32));

    // defer-max (T13): rescale only when max grew past threshold (log2 units)
    if (!__all(mx - m_l <= 8.0f)) {
      const float mn = fmaxf(m_l, mx);
      const float al = __builtin_amdgcn_exp2f(m_l - mn);
      m_l = mn;
      float alq[4];
#pragma unroll
      for (int i = 0; i < 4; ++i) alq[i] = __shfl(al, lh * 4 + i);
#pragma unroll
      for (int db = 0; db < 4; ++db)
#pragma unroll
        for (int i = 0; i < 4; ++i) cacc[db][i] *= alq[i];
#pragma unroll
      for (int i = 0; i < 4; ++i) lacc[i] *= alq[i];
    }

    // P = exp2(S - m), pack via v_cvt_pk_bf16_f32, store to wave-private LDS
#pragma unroll
    for (int jb = 0; jb < 4; ++jb) {
      const float p0 = __builtin_amdgcn_exp2f(st[jb][0] - m_l);
      const float p1 = __builtin_amdgcn_exp2f(st[jb][1] - m_l);
      const float p2 = __builtin_amdgcn_exp2f(st[jb][2] - m_l);
      const float p3 = __builtin_amdgcn_exp2f(st[jb][3] - m_l);
      uint2 pk;
      asm("v_cvt_pk_bf16_f32 %0, %1, %2" : "=v"(pk.x) : "v"(p0), "v"(p1));
      asm("v_cvt_pk_bf16_f32 %0, %1, %2" : "=v"(pk.y) : "v"(p2), "v"(p3));
      *(uint2*)(ps + ll * 64 + (((jb * 2 + (lh >> 1)) ^ (ll & 7)) * 8) + (lh & 1) * 4) = pk;
    }

    asm volatile("s_waitcnt lgkmcnt(0)" ::: "memory");
    __builtin_amdgcn_sched_barrier(0);

    // ctx += P * V ; row-sums l += P @ 1 (same A-fragment, free B)
    __builtin_amdgcn_s_setprio(1);
#pragma unroll
    for (int kk = 0; kk < 2; ++kk) {
      bf16x8 pf = *(const bf16x8*)(ps + ll * 64 + (((kk * 4 + lh) ^ (ll & 7)) * 8));
      lacc = mfma16(pf, ones, lacc);
#pragma unroll
      for (int db = 0; db < 4; ++db) {
        const int vr = db * 16 + ll;
        bf16x8 vf = *(const bf16x8*)(Vs[b] + vr * 64 + (((kk * 4 + lh) ^ (vr & 7)) * 8));
        cacc[db] = mfma16(pf, vf, cacc[db]);
      }
    }
    __builtin_amdgcn_s_setprio(0);
    __syncthreads();  // drains staged loads for kt+1, protects dbuf
  }

  const int bb = bh >> 4, hh = bh & 15;
#pragma unroll
  for (int db = 0; db < 4; ++db)
#pragma unroll
    for (int i = 0; i < 4; ++i) {
      const float v = cacc[db][i] / lacc[i];
      const size_t orow = (size_t)bb * 2048 + q0 + lh * 4 + i;
      const size_t ocol = (size_t)hh * 64 + db * 16 + ll;
      ctx[orow * 1024 + ocol] = f2b(v);
    }
}

// --- fused residual + up-to-4 partials + bias + LayerNorm (row = 1024 f32) --
__global__ __launch_bounds__(256) void ln_fused(
    const float* __restrict__ a,  const float* __restrict__ b0,
    const float* __restrict__ b1, const float* __restrict__ b2,
    const float* __restrict__ b3, const float* __restrict__ bias,
    const float* __restrict__ g,  const float* __restrict__ be,
    float* __restrict__ ho, u16* __restrict__ hb)
{
  const int row = blockIdx.x;
  const int t = threadIdx.x;
  const size_t base = (size_t)row * 1024 + t * 4;
  float4 xa = *(const float4*)(a + base);
  float4 xb = *(const float4*)(b0 + base);
  float v0 = xa.x + xb.x, v1 = xa.y + xb.y, v2 = xa.z + xb.z, v3 = xa.w + xb.w;
  if (b1) {
    float4 xc = *(const float4*)(b1 + base);
    v0 += xc.x; v1 += xc.y; v2 += xc.z; v3 += xc.w;
  }
  if (b2) {
    float4 xc = *(const float4*)(b2 + base);
    v0 += xc.x; v1 += xc.y; v2 += xc.z; v3 += xc.w;
  }
  if (b3) {
    float4 xc = *(const float4*)(b3 + base);
    v0 += xc.x; v1 += xc.y; v2 += xc.z; v3 += xc.w;
  }
  if (bias) {
    float4 xd = *(const float4*)(bias + t * 4);
    v0 += xd.x; v1 += xd.y; v2 += xd.z; v3 += xd.w;
  }
  float s = v0 + v1 + v2 + v3;
  float ss = v0 * v0 + v1 * v1 + v2 * v2 + v3 * v3;
#pragma unroll
  for (int d = 1; d < 64; d <<= 1) {
    s += __shfl_xor(s, d);
    ss += __shfl_xor(ss, d);
  }
  __shared__ float red[8];
  const int w = t >> 6, lid = t & 63;
  if (lid == 0) { red[w] = s; red[4 + w] = ss; }
  __syncthreads();
  s = red[0] + red[1] + red[2] + red[3];
  ss = red[4] + red[5] + red[6] + red[7];
  const float mean = s * (1.0f / 1024.0f);
  const float var = ss * (1.0f / 1024.0f) - mean * mean;
  const float rstd = rsqrtf(var + 1e-5f);
  const float vv[4] = {v0, v1, v2, v3};
#pragma unroll
  for (int i = 0; i < 4; ++i) {
    const int col = t * 4 + i;
    const float hv = (vv[i] - mean) * rstd * g[col] + be[col];
    if (ho) ho[base + i] = hv;
    if (hb) hb[base + i] = f2b(hv);
  }
}

// ---------------------------------------------------------------------------
extern "C" void kernel_launch(void* const* d_in, const int* in_sizes, int n_in,
                              void* d_out, int out_size, void* d_ws, size_t ws_size,
                              hipStream_t stream) {
  const float* x   = (const float*)d_in[0];
  const float* wq  = (const float*)d_in[1];
  const float* wk  = (const float*)d_in[2];
  const float* wv  = (const float*)d_in[3];
  const float* wo  = (const float*)d_in[4];
  const float* bo  = (const float*)d_in[5];
  const float* g1  = (const float*)d_in[6];
  const float* b1  = (const float*)d_in[7];
  const float* w1  = (const float*)d_in[8];
  const float* bf1 = (const float*)d_in[9];
  const float* w2  = (const float*)d_in[10];
  const float* bf2 = (const float*)d_in[11];
  const float* g2  = (const float*)d_in[12];
  const float* b2  = (const float*)d_in[13];

  char* ws = (char*)d_ws;
  const size_t MB = 1u << 20;
  // liveness plan (producer -> last consumer); NO overlapping live ranges:
  u16* xb    = (u16*)(ws + 0);           //  0-8   conv -> QKV
  u16* wqkv  = (u16*)(ws + 8 * MB);      //  8-14  conv -> QKV
  u16* wob   = (u16*)(ws + 14 * MB);     // 14-16  conv -> WO
  u16* w1b   = (u16*)(ws + 16 * MB);     // 16-24  conv -> FF1
  u16* w2b   = (u16*)(ws + 24 * MB);     // 24-32  conv -> FF2
  u16* qb    = (u16*)(ws + 32 * MB);     // 32-40  QKV -> attn
  u16* kb    = (u16*)(ws + 40 * MB);     // 40-48  QKV -> attn
  u16* vtb   = (u16*)(ws + 48 * MB);     // 48-56  QKV -> attn
  u16* ctxb  = (u16*)(ws + 56 * MB);     // 56-64  attn -> WO
  float* pA   = (float*)(ws + 64 * MB);  // 64-80  WO p0 -> LN1; FF2 p0 -> LN2
  float* hbuf = (float*)(ws + 80 * MB);  // 80-96  LN1 -> LN2
  u16* hbb   = (u16*)(ws + 96 * MB);     // 96-104 LN1 -> FF1
  float* wo_p1 = (float*)(ws + 32 * MB); // 32-48  WO p1 -> LN1 (qb/kb dead)
  u16* ff1   = (u16*)(ws + 32 * MB);     // 32-64  FF1 -> FF2 (wo_p1/vtb/ctxb dead)
  float* f2_p1 = (float*)(ws + 0);       //  0-16  FF2 p1 -> LN2 (xb/wqkv/wob dead)

  // all fp32 -> bf16 conversions in one launch
  f2b_all<<<8192, 256, 0, stream>>>(x, wq, wk, wv, wo, w1, w2, xb, wqkv, wob, w1b, w2b);

  // fused QKV projection (q pre-scaled by 0.125*log2e): M=4096 N=3072 K=1024
  gemm_bt<0><<<768, 256, 0, stream>>>(xb, wqkv, nullptr, qb, kb, vtb, 3072, 1024, 1024, 768);
  // attention
  attn_fwd<<<1024, 256, 0, stream>>>(qb, kb, vtb, ctxb);
  // output projection, split-k=2 (bias bo folded into LN1): M=4096 N=1024 K=1024
  gemm_bt<1><<<512, 256, 0, stream>>>(ctxb, wob, nullptr, pA, wo_p1, nullptr, 1024, 1024, 512, 256);
  // h = LN(x + wo_p0 + wo_p1 + bo)
  ln_fused<<<4096, 256, 0, stream>>>(x, pA, wo_p1, nullptr, nullptr, bo, g1, b1, hbuf, hbb);
  // ff1 = gelu(h @ w1^T + bf1): M=4096 N=4096 K=1024
  gemm_bt<2><<<1024, 256, 0, stream>>>(hbb, w1b, bf1, ff1, nullptr, nullptr, 4096, 1024, 1024, 1024);
  // ff2 = ff1 @ w2^T, split-k=2 (bias bf2 folded into LN2): M=4096 N=1024 K=4096
  gemm_bt<1><<<512, 256, 0, stream>>>(ff1, w2b, nullptr, pA, f2_p1, nullptr, 1024, 4096, 2048, 256);
  // out = LN(h + p0 + p1 + bf2)
  ln_fused<<<4096, 256, 0, stream>>>(hbuf, pA, f2_p1, nullptr, nullptr, bf2, g2, b2,
                                     (float*)d_out, nullptr);
}

// Round 8
// 255.695 us; speedup vs baseline: 1.2433x; 1.0477x over previous
//
#include <hip/hip_runtime.h>
#include <hip/hip_bf16.h>
#include <stdint.h>

typedef __bf16 bf16x8 __attribute__((ext_vector_type(8)));
typedef float  f32x4  __attribute__((ext_vector_type(4)));
typedef unsigned short u16;
typedef u16 u16x8 __attribute__((ext_vector_type(8)));

__device__ __forceinline__ u16 f2b(float f) {
  uint32_t u = __builtin_bit_cast(uint32_t, f);
  u += 0x7fffu + ((u >> 16) & 1u);
  return (u16)(u >> 16);
}

__device__ __forceinline__ f32x4 mfma16(bf16x8 a, bf16x8 b, f32x4 c) {
  return __builtin_amdgcn_mfma_f32_16x16x32_bf16(a, b, c, 0, 0, 0);
}

__device__ __forceinline__ void gload_lds16(const void* g, void* l) {
  __builtin_amdgcn_global_load_lds(
      (const __attribute__((address_space(1))) void*)g,
      (__attribute__((address_space(3))) void*)l, 16, 0, 0);
}

// ------------- merged fp32 -> bf16 convert (all 7 tensors, 1 launch) --------
__global__ void f2b_all(const float* __restrict__ x,  const float* __restrict__ wq,
                        const float* __restrict__ wk, const float* __restrict__ wv,
                        const float* __restrict__ wo, const float* __restrict__ w1,
                        const float* __restrict__ w2,
                        u16* __restrict__ xb, u16* __restrict__ wqkvb,
                        u16* __restrict__ wob, u16* __restrict__ w1b,
                        u16* __restrict__ w2b) {
  const int i = blockIdx.x * blockDim.x + threadIdx.x;  // elem8 index, 2097152 total
  const float* src; u16* dst; int off;
  if (i < 524288)        { src = x;  dst = xb;              off = i; }
  else if (i < 655360)   { src = wq; dst = wqkvb;           off = i - 524288; }
  else if (i < 786432)   { src = wk; dst = wqkvb + 1048576; off = i - 655360; }
  else if (i < 917504)   { src = wv; dst = wqkvb + 2097152; off = i - 786432; }
  else if (i < 1048576)  { src = wo; dst = wob;             off = i - 917504; }
  else if (i < 1572864)  { src = w1; dst = w1b;             off = i - 1048576; }
  else                   { src = w2; dst = w2b;             off = i - 1572864; }
  const float4* p = (const float4*)src + (size_t)off * 2;
  float4 a = p[0], b = p[1];
  u16x8 r;
  r[0] = f2b(a.x); r[1] = f2b(a.y); r[2] = f2b(a.z); r[3] = f2b(a.w);
  r[4] = f2b(b.x); r[5] = f2b(b.y); r[6] = f2b(b.z); r[7] = f2b(b.w);
  *((u16x8*)dst + off) = r;
}

// ---------------- GEMM (proven): 128x128, BK=32, 2-phase double-buffer ------
// C[M][N] = A[M][K] * W[N][K]^T
// MODE 0: QKV scatter (o0=q*(0.125*log2e), o1=k, o2=vt)  [no split]
// MODE 1: fp32 partial out, NO bias (summed in ln_fused)  [split-k via ntiles]
// MODE 2: bf16 out + bias + tanh-gelu                     [no split]
template<int MODE>
__global__ __launch_bounds__(256, 3) void gemm_bt(
    const u16* __restrict__ A, const u16* __restrict__ W,
    const float* __restrict__ bias,
    void* __restrict__ o0, void* __restrict__ o1, void* __restrict__ o2,
    int Nsz, int Kstride, int Klen, int ntiles)
{
  __shared__ u16 As[2][128 * 32];
  __shared__ u16 Bs[2][128 * 32];
  const int nbn = Nsz >> 7;
  int bid = blockIdx.x;
  bid = (bid & 7) * ((int)gridDim.x >> 3) + (bid >> 3);  // XCD-aware swizzle (grid%8==0)
  const int tile = (MODE == 1) ? (bid % ntiles) : bid;
  const int sid  = (MODE == 1) ? (bid / ntiles) : 0;
  const int koff = sid * Klen;
  const int bm = tile / nbn;
  const int bn = tile % nbn;
  const int tid = threadIdx.x;
  const int w = tid >> 6, l = tid & 63;
  const int lh = l >> 4, ll = l & 15;
  const int wr = w >> 1, wc = w & 1;

  f32x4 acc[4][4] = {};

  const u16* Ag = A + (size_t)(bm * 128) * Kstride + koff;
  const u16* Wg = W + (size_t)(bn * 128) * Kstride + koff;

  const int flat0 = (w * 2) * 64 + l;
  const int flat1 = (w * 2 + 1) * 64 + l;

  // prologue: stage k-step 0 into buf 0
  {
    gload_lds16(Ag + (size_t)(flat0 >> 2) * Kstride + (flat0 & 3) * 8, As[0] + flat0 * 8);
    gload_lds16(Wg + (size_t)(flat0 >> 2) * Kstride + (flat0 & 3) * 8, Bs[0] + flat0 * 8);
    gload_lds16(Ag + (size_t)(flat1 >> 2) * Kstride + (flat1 & 3) * 8, As[0] + flat1 * 8);
    gload_lds16(Wg + (size_t)(flat1 >> 2) * Kstride + (flat1 & 3) * 8, Bs[0] + flat1 * 8);
  }
  __syncthreads();

  const int NS = Klen >> 5;
  int buf = 0;
  for (int s = 0; s < NS; ++s) {
    if (s + 1 < NS) {  // issue next-tile stage first (loads fly under compute)
      const int k0 = (s + 1) * 32;
      gload_lds16(Ag + (size_t)(flat0 >> 2) * Kstride + k0 + (flat0 & 3) * 8, As[buf ^ 1] + flat0 * 8);
      gload_lds16(Wg + (size_t)(flat0 >> 2) * Kstride + k0 + (flat0 & 3) * 8, Bs[buf ^ 1] + flat0 * 8);
      gload_lds16(Ag + (size_t)(flat1 >> 2) * Kstride + k0 + (flat1 & 3) * 8, As[buf ^ 1] + flat1 * 8);
      gload_lds16(Wg + (size_t)(flat1 >> 2) * Kstride + k0 + (flat1 & 3) * 8, Bs[buf ^ 1] + flat1 * 8);
    }
    bf16x8 af[4], bfr[4];
#pragma unroll
    for (int mi = 0; mi < 4; ++mi)
      af[mi] = *(const bf16x8*)(As[buf] + (wr * 64 + mi * 16 + ll) * 32 + lh * 8);
#pragma unroll
    for (int ni = 0; ni < 4; ++ni)
      bfr[ni] = *(const bf16x8*)(Bs[buf] + (wc * 64 + ni * 16 + ll) * 32 + lh * 8);
    __builtin_amdgcn_s_setprio(1);
#pragma unroll
    for (int mi = 0; mi < 4; ++mi)
#pragma unroll
      for (int ni = 0; ni < 4; ++ni)
        acc[mi][ni] = mfma16(af[mi], bfr[ni], acc[mi][ni]);
    __builtin_amdgcn_s_setprio(0);
    __syncthreads();  // drains vmcnt for staged buf^1 + protects dbuf reuse
    buf ^= 1;
  }

#pragma unroll
  for (int mi = 0; mi < 4; ++mi) {
#pragma unroll
    for (int ni = 0; ni < 4; ++ni) {
      const int col = bn * 128 + wc * 64 + ni * 16 + ll;
#pragma unroll
      for (int i = 0; i < 4; ++i) {
        const int row = bm * 128 + wr * 64 + mi * 16 + lh * 4 + i;
        float v = acc[mi][ni][i];
        if (MODE == 1) {
          float* dst = sid ? (float*)o1 : (float*)o0;
          dst[(size_t)row * Nsz + col] = v;
        } else if (MODE == 2) {
          // tanh-form GELU via exp2: x*sigmoid(2*0.79788456*(x+0.044715x^3))
          float xx = v + bias[col];
          float u = xx * (0.7978845608f + 0.0356774081f * xx * xx);
          float t = __builtin_amdgcn_exp2f(u * 2.8853900818f);
          float r = __builtin_amdgcn_rcpf(1.0f + t);
          ((u16*)o0)[(size_t)row * Nsz + col] = f2b(xx * t * r);
        } else {
          const int which = col >> 10;
          const int e = col & 1023;
          const int hh = e >> 6, dd = e & 63;
          const int bb = row >> 11, nl = row & 2047;
          if (which == 0) {  // q, pre-scaled by (1/sqrt(D)) * log2(e)
            ((u16*)o0)[((size_t)(bb * 16 + hh) * 2048 + nl) * 64 + dd] = f2b(v * 0.18033688f);
          } else if (which == 1) {
            ((u16*)o1)[((size_t)(bb * 16 + hh) * 2048 + nl) * 64 + dd] = f2b(v);
          } else {
            ((u16*)o2)[((size_t)(bb * 16 + hh) * 64 + dd) * 2048 + nl] = f2b(v);
          }
        }
      }
    }
  }
}

// ---------------- flash attention, swapped QK^T, log2 domain, QBLK=32/wave --
// Q,K: bf16 [32][2048][64] (Q pre-scaled); Vt: bf16 [32][64][2048]; ctx: bf16 [4096][1024]
// 4 waves x 32 q-rows = 128 q-rows/block; grid = 16 qtiles * 32 bh = 512
__global__ __launch_bounds__(256, 3) void attn_fwd(
    const u16* __restrict__ Q, const u16* __restrict__ K,
    const u16* __restrict__ Vt, u16* __restrict__ ctx)
{
  __shared__ u16 Ks[2][64 * 64];
  __shared__ u16 Vs[2][64 * 64];
  __shared__ u16 Ps[4][32 * 64];

  const int bh = blockIdx.x & 31;
  const int qt = blockIdx.x >> 5;
  const int tid = threadIdx.x;
  const int w = tid >> 6, l = tid & 63;
  const int lh = l >> 4, ll = l & 15;
  const int q0 = qt * 128 + w * 32;

  bf16x8 qf[2][2];  // [qh][kk]
#pragma unroll
  for (int qh = 0; qh < 2; ++qh) {
    const u16* Qg = Q + ((size_t)bh * 2048 + q0 + qh * 16 + ll) * 64;
#pragma unroll
    for (int kk = 0; kk < 2; ++kk)
      qf[qh][kk] = *(const bf16x8*)(Qg + kk * 32 + lh * 8);
  }

  bf16x8 ones;
  {
    const u16 o = 0x3F80;  // bf16 1.0
#pragma unroll
    for (int i = 0; i < 8; ++i) ones[i] = __builtin_bit_cast(__bf16, o);
  }

  f32x4 cacc[2][4] = {};            // [qh][db]
  f32x4 lacc[2] = {};               // per-query row-sum of P via mfma(P, ones)
  float m_l[2] = {-1e30f, -1e30f};  // running max (log2 domain), query qh*16+ll
  u16* ps = Ps[w];

  const int f0 = tid, f1 = 256 + tid;
  const int r0 = f0 >> 3, s0 = f0 & 7, g0 = (s0 ^ (r0 & 7)) * 8;
  const int r1 = f1 >> 3, s1 = f1 & 7, g1 = (s1 ^ (r1 & 7)) * 8;

  // prologue: stage kt=0 into buf 0 (swizzled source, linear LDS dest)
  {
    gload_lds16(K + ((size_t)bh * 2048 + r0) * 64 + g0, Ks[0] + f0 * 8);
    gload_lds16(Vt + ((size_t)bh * 64 + r0) * 2048 + g0, Vs[0] + f0 * 8);
    gload_lds16(K + ((size_t)bh * 2048 + r1) * 64 + g1, Ks[0] + f1 * 8);
    gload_lds16(Vt + ((size_t)bh * 64 + r1) * 2048 + g1, Vs[0] + f1 * 8);
  }
  __syncthreads();

  for (int kt = 0; kt < 32; ++kt) {
    const int b = kt & 1;
    if (kt < 31) {  // stage kt+1 early; drains only at end-of-tile barrier
      const int kn = (kt + 1) * 64;
      gload_lds16(K + ((size_t)bh * 2048 + kn + r0) * 64 + g0, Ks[b ^ 1] + f0 * 8);
      gload_lds16(Vt + ((size_t)bh * 64 + r0) * 2048 + kn + g0, Vs[b ^ 1] + f0 * 8);
      gload_lds16(K + ((size_t)bh * 2048 + kn + r1) * 64 + g1, Ks[b ^ 1] + f1 * 8);
      gload_lds16(Vt + ((size_t)bh * 64 + r1) * 2048 + kn + g1, Vs[b ^ 1] + f1 * 8);
    }

    // S^T = K Q^T (log2 domain), both q-halves sharing each K fragment
    f32x4 st[2][4];
    __builtin_amdgcn_s_setprio(1);
#pragma unroll
    for (int jb = 0; jb < 4; ++jb) {
      f32x4 a0 = {}, a1 = {};
#pragma unroll
      for (int kk = 0; kk < 2; ++kk) {
        const int r = jb * 16 + ll;
        bf16x8 kf = *(const bf16x8*)(Ks[b] + r * 64 + (((kk * 4 + lh) ^ (r & 7)) * 8));
        a0 = mfma16(kf, qf[0][kk], a0);
        a1 = mfma16(kf, qf[1][kk], a1);
      }
      st[0][jb] = a0; st[1][jb] = a1;
    }
    __builtin_amdgcn_s_setprio(0);

    // per-lane max over 16 regs per q-half + cross-lh reduce
    float mx[2];
#pragma unroll
    for (int qh = 0; qh < 2; ++qh) {
      float m = fmaxf(fmaxf(fmaxf(st[qh][0][0], st[qh][0][1]), fmaxf(st[qh][0][2], st[qh][0][3])),
                      fmaxf(fmaxf(st[qh][1][0], st[qh][1][1]), fmaxf(st[qh][1][2], st[qh][1][3])));
      m = fmaxf(m, fmaxf(fmaxf(fmaxf(st[qh][2][0], st[qh][2][1]), fmaxf(st[qh][2][2], st[qh][2][3])),
                         fmaxf(fmaxf(st[qh][3][0], st[qh][3][1]), fmaxf(st[qh][3][2], st[qh][3][3]))));
      m = fmaxf(m, __shfl_xor(m, 16));
      m = fmaxf(m, __shfl_xor(m, 32));
      mx[qh] = m;
    }

    // defer-max (T13): rescale only when max grew past threshold (log2 units)
    if (!__all(mx[0] - m_l[0] <= 8.0f && mx[1] - m_l[1] <= 8.0f)) {
#pragma unroll
      for (int qh = 0; qh < 2; ++qh) {
        const float mn = fmaxf(m_l[qh], mx[qh]);
        const float al = __builtin_amdgcn_exp2f(m_l[qh] - mn);
        m_l[qh] = mn;
        float alq[4];
#pragma unroll
        for (int i = 0; i < 4; ++i) alq[i] = __shfl(al, lh * 4 + i);
#pragma unroll
        for (int db = 0; db < 4; ++db)
#pragma unroll
          for (int i = 0; i < 4; ++i) cacc[qh][db][i] *= alq[i];
#pragma unroll
        for (int i = 0; i < 4; ++i) lacc[qh][i] *= alq[i];
      }
    }

    // P = exp2(S - m), pack via v_cvt_pk_bf16_f32, store to wave-private LDS
#pragma unroll
    for (int qh = 0; qh < 2; ++qh)
#pragma unroll
      for (int jb = 0; jb < 4; ++jb) {
        const float p0 = __builtin_amdgcn_exp2f(st[qh][jb][0] - m_l[qh]);
        const float p1 = __builtin_amdgcn_exp2f(st[qh][jb][1] - m_l[qh]);
        const float p2 = __builtin_amdgcn_exp2f(st[qh][jb][2] - m_l[qh]);
        const float p3 = __builtin_amdgcn_exp2f(st[qh][jb][3] - m_l[qh]);
        uint2 pk;
        asm("v_cvt_pk_bf16_f32 %0, %1, %2" : "=v"(pk.x) : "v"(p0), "v"(p1));
        asm("v_cvt_pk_bf16_f32 %0, %1, %2" : "=v"(pk.y) : "v"(p2), "v"(p3));
        *(uint2*)(ps + (qh * 16 + ll) * 64 +
                  (((jb * 2 + (lh >> 1)) ^ (ll & 7)) * 8) + (lh & 1) * 4) = pk;
      }

    asm volatile("s_waitcnt lgkmcnt(0)" ::: "memory");
    __builtin_amdgcn_sched_barrier(0);

    // ctx += P * V ; row-sums l += P @ 1 ; V fragments shared across q-halves
    __builtin_amdgcn_s_setprio(1);
#pragma unroll
    for (int kk = 0; kk < 2; ++kk) {
      bf16x8 pf0 = *(const bf16x8*)(ps + ll * 64 + (((kk * 4 + lh) ^ (ll & 7)) * 8));
      bf16x8 pf1 = *(const bf16x8*)(ps + (16 + ll) * 64 + (((kk * 4 + lh) ^ (ll & 7)) * 8));
      lacc[0] = mfma16(pf0, ones, lacc[0]);
      lacc[1] = mfma16(pf1, ones, lacc[1]);
#pragma unroll
      for (int db = 0; db < 4; ++db) {
        const int vr = db * 16 + ll;
        bf16x8 vf = *(const bf16x8*)(Vs[b] + vr * 64 + (((kk * 4 + lh) ^ (vr & 7)) * 8));
        cacc[0][db] = mfma16(pf0, vf, cacc[0][db]);
        cacc[1][db] = mfma16(pf1, vf, cacc[1][db]);
      }
    }
    __builtin_amdgcn_s_setprio(0);
    __syncthreads();  // drains staged loads for kt+1, protects dbuf
  }

  const int bb = bh >> 4, hh = bh & 15;
#pragma unroll
  for (int qh = 0; qh < 2; ++qh)
#pragma unroll
    for (int db = 0; db < 4; ++db)
#pragma unroll
      for (int i = 0; i < 4; ++i) {
        const float v = cacc[qh][db][i] / lacc[qh][i];
        const size_t orow = (size_t)bb * 2048 + q0 + qh * 16 + lh * 4 + i;
        const size_t ocol = (size_t)hh * 64 + db * 16 + ll;
        ctx[orow * 1024 + ocol] = f2b(v);
      }
}

// --- fused residual + up-to-4 partials + bias + LayerNorm (row = 1024 f32) --
__global__ __launch_bounds__(256) void ln_fused(
    const float* __restrict__ a,  const float* __restrict__ b0,
    const float* __restrict__ b1, const float* __restrict__ b2,
    const float* __restrict__ b3, const float* __restrict__ bias,
    const float* __restrict__ g,  const float* __restrict__ be,
    float* __restrict__ ho, u16* __restrict__ hb)
{
  const int row = blockIdx.x;
  const int t = threadIdx.x;
  const size_t base = (size_t)row * 1024 + t * 4;
  float4 xa = *(const float4*)(a + base);
  float4 xb = *(const float4*)(b0 + base);
  float v0 = xa.x + xb.x, v1 = xa.y + xb.y, v2 = xa.z + xb.z, v3 = xa.w + xb.w;
  if (b1) {
    float4 xc = *(const float4*)(b1 + base);
    v0 += xc.x; v1 += xc.y; v2 += xc.z; v3 += xc.w;
  }
  if (b2) {
    float4 xc = *(const float4*)(b2 + base);
    v0 += xc.x; v1 += xc.y; v2 += xc.z; v3 += xc.w;
  }
  if (b3) {
    float4 xc = *(const float4*)(b3 + base);
    v0 += xc.x; v1 += xc.y; v2 += xc.z; v3 += xc.w;
  }
  if (bias) {
    float4 xd = *(const float4*)(bias + t * 4);
    v0 += xd.x; v1 += xd.y; v2 += xd.z; v3 += xd.w;
  }
  float s = v0 + v1 + v2 + v3;
  float ss = v0 * v0 + v1 * v1 + v2 * v2 + v3 * v3;
#pragma unroll
  for (int d = 1; d < 64; d <<= 1) {
    s += __shfl_xor(s, d);
    ss += __shfl_xor(ss, d);
  }
  __shared__ float red[8];
  const int w = t >> 6, lid = t & 63;
  if (lid == 0) { red[w] = s; red[4 + w] = ss; }
  __syncthreads();
  s = red[0] + red[1] + red[2] + red[3];
  ss = red[4] + red[5] + red[6] + red[7];
  const float mean = s * (1.0f / 1024.0f);
  const float var = ss * (1.0f / 1024.0f) - mean * mean;
  const float rstd = rsqrtf(var + 1e-5f);
  const float vv[4] = {v0, v1, v2, v3};
#pragma unroll
  for (int i = 0; i < 4; ++i) {
    const int col = t * 4 + i;
    const float hv = (vv[i] - mean) * rstd * g[col] + be[col];
    if (ho) ho[base + i] = hv;
    if (hb) hb[base + i] = f2b(hv);
  }
}

// ---------------------------------------------------------------------------
extern "C" void kernel_launch(void* const* d_in, const int* in_sizes, int n_in,
                              void* d_out, int out_size, void* d_ws, size_t ws_size,
                              hipStream_t stream) {
  const float* x   = (const float*)d_in[0];
  const float* wq  = (const float*)d_in[1];
  const float* wk  = (const float*)d_in[2];
  const float* wv  = (const float*)d_in[3];
  const float* wo  = (const float*)d_in[4];
  const float* bo  = (const float*)d_in[5];
  const float* g1  = (const float*)d_in[6];
  const float* b1  = (const float*)d_in[7];
  const float* w1  = (const float*)d_in[8];
  const float* bf1 = (const float*)d_in[9];
  const float* w2  = (const float*)d_in[10];
  const float* bf2 = (const float*)d_in[11];
  const float* g2  = (const float*)d_in[12];
  const float* b2  = (const float*)d_in[13];

  char* ws = (char*)d_ws;
  const size_t MB = 1u << 20;
  // liveness plan (producer -> last consumer); NO overlapping live ranges:
  u16* xb    = (u16*)(ws + 0);           //  0-8   conv -> QKV
  u16* wqkv  = (u16*)(ws + 8 * MB);      //  8-14  conv -> QKV
  u16* wob   = (u16*)(ws + 14 * MB);     // 14-16  conv -> WO
  u16* w1b   = (u16*)(ws + 16 * MB);     // 16-24  conv -> FF1
  u16* w2b   = (u16*)(ws + 24 * MB);     // 24-32  conv -> FF2
  u16* qb    = (u16*)(ws + 32 * MB);     // 32-40  QKV -> attn
  u16* kb    = (u16*)(ws + 40 * MB);     // 40-48  QKV -> attn
  u16* vtb   = (u16*)(ws + 48 * MB);     // 48-56  QKV -> attn
  u16* ctxb  = (u16*)(ws + 56 * MB);     // 56-64  attn -> WO
  float* pA   = (float*)(ws + 64 * MB);  // 64-80  WO p0 -> LN1; FF2 p0 -> LN2
  float* hbuf = (float*)(ws + 80 * MB);  // 80-96  LN1 -> LN2
  u16* hbb   = (u16*)(ws + 96 * MB);     // 96-104 LN1 -> FF1
  float* wo_p1 = (float*)(ws + 32 * MB); // 32-48  WO p1 -> LN1 (qb/kb dead)
  u16* ff1   = (u16*)(ws + 32 * MB);     // 32-64  FF1 -> FF2 (wo_p1/vtb/ctxb dead)
  float* f2_p1 = (float*)(ws + 0);       //  0-16  FF2 p1 -> LN2 (xb/wqkv/wob dead)

  // all fp32 -> bf16 conversions in one launch
  f2b_all<<<8192, 256, 0, stream>>>(x, wq, wk, wv, wo, w1, w2, xb, wqkv, wob, w1b, w2b);

  // fused QKV projection (q pre-scaled by 0.125*log2e): M=4096 N=3072 K=1024
  gemm_bt<0><<<768, 256, 0, stream>>>(xb, wqkv, nullptr, qb, kb, vtb, 3072, 1024, 1024, 768);
  // attention (QBLK=32/wave, 128 q-rows/block)
  attn_fwd<<<512, 256, 0, stream>>>(qb, kb, vtb, ctxb);
  // output projection, split-k=2 (bias bo folded into LN1): M=4096 N=1024 K=1024
  gemm_bt<1><<<512, 256, 0, stream>>>(ctxb, wob, nullptr, pA, wo_p1, nullptr, 1024, 1024, 512, 256);
  // h = LN(x + wo_p0 + wo_p1 + bo)
  ln_fused<<<4096, 256, 0, stream>>>(x, pA, wo_p1, nullptr, nullptr, bo, g1, b1, hbuf, hbb);
  // ff1 = gelu(h @ w1^T + bf1): M=4096 N=4096 K=1024
  gemm_bt<2><<<1024, 256, 0, stream>>>(hbb, w1b, bf1, ff1, nullptr, nullptr, 4096, 1024, 1024, 1024);
  // ff2 = ff1 @ w2^T, split-k=2 (bias bf2 folded into LN2): M=4096 N=1024 K=4096
  gemm_bt<1><<<512, 256, 0, stream>>>(ff1, w2b, nullptr, pA, f2_p1, nullptr, 1024, 4096, 2048, 256);
  // out = LN(h + p0 + p1 + bf2)
  ln_fused<<<4096, 256, 0, stream>>>(hbuf, pA, f2_p1, nullptr, nullptr, bf2, g2, b2,
                                     (float*)d_out, nullptr);
}